// Round 5
// baseline (72.529 us; speedup 1.0000x reference)
//
#include <hip/hip_runtime.h>
#include <hip/hip_fp16.h>

#define H 1024
#define W 2048
#define HW (H * W)
#define LOG19 2.9444389791664403f
#define TY 8        // rows per block
#define NT 576      // 9 waves
#define NVERT 528   // vertical threads: 528 x 2 = 1056 padded cols
#define BCOLS 1024  // output cols per block
#define PCOLS 1056  // padded cols (±16 halo)
#define NG 132      // 8-col groups
#define GRP 41      // lcnt words/group (41 mod 32 = 9, coprime)
#define LGS 9       // lent words/group
#define GSS 11      // gsum words/group: 10 u16x2 + 1 float

typedef __attribute__((ext_vector_type(4))) float f32x4;
typedef __attribute__((ext_vector_type(2))) unsigned int u32x2;
typedef __attribute__((ext_vector_type(4))) unsigned int u32x4;

static __device__ __forceinline__ unsigned short f2h_bits(float f) {
    __half h = __float2half_rn(f);
    unsigned short b;
    __builtin_memcpy(&b, &h, 2);
    return b;
}
static __device__ __forceinline__ float h2f_bits(unsigned int b) {
    unsigned short s = (unsigned short)b;
    __half h;
    __builtin_memcpy(&h, &s, 2);
    return __half2float(h);
}

// ---------------- K1: softmax entropy + argmax -> packed u32/px ----------------
__global__ __launch_bounds__(256) void k1_entropy_argmax(
    const float* __restrict__ logit,
    unsigned int* __restrict__ packed) {
    int q = blockIdx.x * 256 + threadIdx.x;
    int p0 = q * 4;
    f32x4 v[19];
#pragma unroll
    for (int c = 0; c < 19; c++)
        v[c] = *reinterpret_cast<const f32x4*>(logit + (size_t)c * HW + p0);
    f32x4 m = v[0];
    int am[4] = {0, 0, 0, 0};
#pragma unroll
    for (int c = 1; c < 19; c++) {
#pragma unroll
        for (int j = 0; j < 4; j++)
            if (v[c][j] > m[j]) { m[j] = v[c][j]; am[j] = c; }
    }
    f32x4 S = (f32x4)(0.f), T = (f32x4)(0.f);
#pragma unroll
    for (int c = 0; c < 19; c++) {
#pragma unroll
        for (int j = 0; j < 4; j++) {
            float d = v[c][j] - m[j];
            float e = __expf(d);
            S[j] += e;
            T[j] += d * e;
        }
    }
    u32x4 w;
#pragma unroll
    for (int j = 0; j < 4; j++) {
        float ent = (__logf(S[j]) - T[j] / S[j]) * (1.0f / LOG19);
        w[j] = (unsigned int)f2h_bits(ent) | ((unsigned int)am[j] << 24);
    }
    *reinterpret_cast<u32x4*>(packed + p0) = w;
}

// ---------------- K23: fused box + score ----------------
// grid = 128 y-strips x 2 col-halves (XCD-chunked). 576 threads.
// Vertical: 528 threads x 2 padded cols, u8x4-SWAR 33-tap sliding sums.
// Publish: elements + shfl-reduced 8-col group sums per row, 2-row dbuf.
// Horizontal: 256 threads (2 rows x 128 thr x 8 px), warm-up = 4 groups + 1 el.
#define VACC(yy, SGN)                                                                   \
    if (vvalid) {                                                                       \
        u32x2 pw = *reinterpret_cast<const u32x2*>(packed + (size_t)(yy)*W + gcol0);    \
        _Pragma("unroll") for (int j = 0; j < 2; j++) {                                 \
            unsigned int wv = pw[j];                                                    \
            unsigned int cc = wv >> 24;                                                 \
            unsigned int wi = cc >> 2, bit = 1u << ((cc & 3u) * 8u);                    \
            _Pragma("unroll") for (int k = 0; k < 5; k++)                               \
                vc[j * 5 + k] SGN## = (wi == (unsigned)k) ? bit : 0u;                   \
            ve[j] SGN## = h2f_bits(wv);                                                 \
        }                                                                               \
    }
#define VSLIDE(y)                         \
    {                                     \
        int ya = (y) + 17, yr = (y) - 16; \
        if (ya < H) VACC(ya, +)           \
        if (yr >= 0) VACC(yr, -)          \
    }
#define PUBLISH(b)                                                              \
    if (tid < NVERT) {                                                          \
        unsigned int ps[10];                                                    \
        float pe = ve[0] + ve[1];                                               \
        _Pragma("unroll") for (int k = 0; k < 5; k++) {                         \
            ps[2 * k] = (vc[k] & 0x00FF00FFu) + (vc[5 + k] & 0x00FF00FFu);      \
            ps[2 * k + 1] = ((vc[k] >> 8) & 0x00FF00FFu) +                      \
                            ((vc[5 + k] >> 8) & 0x00FF00FFu);                   \
        }                                                                       \
        int g = tid >> 2, sl0 = (2 * tid) & 7;                                  \
        _Pragma("unroll") for (int k = 0; k < 5; k++) {                         \
            lcnt[b][g * GRP + sl0 * 5 + k] = vc[k];                             \
            lcnt[b][g * GRP + (sl0 + 1) * 5 + k] = vc[5 + k];                   \
        }                                                                       \
        lent[b][g * LGS + sl0] = ve[0];                                         \
        lent[b][g * LGS + sl0 + 1] = ve[1];                                     \
        _Pragma("unroll") for (int q = 0; q < 10; q++) {                        \
            ps[q] += __shfl_xor(ps[q], 1);                                      \
            ps[q] += __shfl_xor(ps[q], 2);                                      \
        }                                                                       \
        pe += __shfl_xor(pe, 1);                                                \
        pe += __shfl_xor(pe, 2);                                                \
        if ((tid & 3) == 0) {                                                   \
            _Pragma("unroll") for (int q = 0; q < 10; q++)                      \
                gsum[b][g * GSS + q] = ps[q];                                   \
            gsum[b][g * GSS + 10] = __float_as_uint(pe);                        \
        }                                                                       \
    }

__global__ __launch_bounds__(NT) void k23_box_score(
    const unsigned int* __restrict__ packed,
    float* __restrict__ out_score,
    float* __restrict__ out_imp,
    float* __restrict__ out_unc) {
    __shared__ float lut[1090];                 // n*ln(n)
    __shared__ unsigned int lcnt[2][NG * GRP];  // per-col u8x4 counts
    __shared__ float lent[2][NG * LGS];         // per-col entropy sums
    __shared__ unsigned int gsum[2][NG * GSS];  // 8-col group sums
    int tid = threadIdx.x;
    int bid = blockIdx.x;
    // XCD-chunked: 16 adjacent strips (x2 halves) per XCD
    int xcd = bid & 7, idx = bid >> 3;
    int strip = xcd * 16 + (idx >> 1);
    int colbase = (idx & 1) * BCOLS;
    int y0 = strip * TY;

    for (int n = tid; n < 1090; n += NT)
        lut[n] = n ? (float)n * __logf((float)n) : 0.f;

    int gcol0 = colbase - 16 + 2 * tid;  // 2 cols/thread, padded
    bool vvalid = (tid < NVERT) && ((unsigned)gcol0 < (unsigned)W);
    unsigned int vc[10];
#pragma unroll
    for (int i = 0; i < 10; i++) vc[i] = 0u;
    float ve[2] = {0.f, 0.f};
    {
        int ylo = max(y0 - 16, 0), yhi = min(y0 + 16, H - 1);
        for (int yy = ylo; yy <= yhi; yy++) VACC(yy, +)
    }

#pragma unroll
    for (int p = 0; p < TY / 2; p++) {
        int yA = y0 + 2 * p;
        PUBLISH(0)
        VSLIDE(yA)  // -> row yA+1
        PUBLISH(1)
        __syncthreads();

        if (tid < 256) {
            int rsel = tid >> 7;  // which buffered row
            int hq = tid & 127;
            int x0h = hq * 8;  // block-local out col
            int y = yA + rsel;
            unsigned int ha[10];
            float hes;
            {  // warm-up: groups hq..hq+3 + element at padded idx x0h+32
#pragma unroll
                for (int q = 0; q < 10; q++)
                    ha[q] = gsum[rsel][hq * GSS + q] + gsum[rsel][(hq + 1) * GSS + q] +
                            gsum[rsel][(hq + 2) * GSS + q] + gsum[rsel][(hq + 3) * GSS + q];
                hes = __uint_as_float(gsum[rsel][hq * GSS + 10]) +
                      __uint_as_float(gsum[rsel][(hq + 1) * GSS + 10]) +
                      __uint_as_float(gsum[rsel][(hq + 2) * GSS + 10]) +
                      __uint_as_float(gsum[rsel][(hq + 3) * GSS + 10]);
#pragma unroll
                for (int k = 0; k < 5; k++) {
                    unsigned int wv = lcnt[rsel][(hq + 4) * GRP + k];
                    ha[2 * k] += wv & 0x00FF00FFu;
                    ha[2 * k + 1] += (wv >> 8) & 0x00FF00FFu;
                }
                hes += lent[rsel][(hq + 4) * LGS];
            }
            int rcount = min(y + 16, H - 1) - max(y - 16, 0) + 1;
            f32x4 osc[2], oim[2], oun[2];
#pragma unroll
            for (int s = 0; s < 8; s++) {
                int gx = colbase + x0h + s;
                int ccount = min(gx + 16, W - 1) - max(gx - 16, 0) + 1;
                int Tw = rcount * ccount;
                float invT = 1.0f / (float)Tw;
                float sum = 0.f;
#pragma unroll
                for (int k = 0; k < 5; k++) {
                    unsigned int a = ha[2 * k], b = ha[2 * k + 1];
                    sum += lut[a & 0xFFFFu] + lut[b & 0xFFFFu] + lut[a >> 16];
                    if (k < 4) sum += lut[b >> 16];
                }
                float imp = (lut[Tw] - sum) * invT * (1.0f / LOG19);
                float unc = hes * invT;
                osc[s >> 2][s & 3] = imp * unc;
                oim[s >> 2][s & 3] = imp;
                oun[s >> 2][s & 3] = unc;
                if (s < 7) {  // slide padded window [x0h+s, x0h+s+32] -> +1
                    int ga = hq + ((s + 33) >> 3), ja = (s + 33) & 7;
                    hes += lent[rsel][ga * LGS + ja] - lent[rsel][hq * LGS + s];
#pragma unroll
                    for (int k = 0; k < 5; k++) {
                        unsigned int wa = lcnt[rsel][ga * GRP + ja * 5 + k];
                        unsigned int wr = lcnt[rsel][hq * GRP + s * 5 + k];
                        ha[2 * k] += (wa & 0x00FF00FFu) - (wr & 0x00FF00FFu);
                        ha[2 * k + 1] += ((wa >> 8) & 0x00FF00FFu) - ((wr >> 8) & 0x00FF00FFu);
                    }
                }
            }
            size_t qo = (size_t)y * W + colbase + x0h;
            *reinterpret_cast<f32x4*>(out_score + qo) = osc[0];
            *reinterpret_cast<f32x4*>(out_score + qo + 4) = osc[1];
            *reinterpret_cast<f32x4*>(out_imp + qo) = oim[0];
            *reinterpret_cast<f32x4*>(out_imp + qo + 4) = oim[1];
            *reinterpret_cast<f32x4*>(out_unc + qo) = oun[0];
            *reinterpret_cast<f32x4*>(out_unc + qo + 4) = oun[1];
        }
        // next-pair vertical slide AFTER the sync: vertical-only threads
        // prefetch while tid<256 run the horizontal phase above
        if (p < TY / 2 - 1) VSLIDE(yA + 1)
        __syncthreads();  // horizontal reads done before next publish
    }
}

extern "C" void kernel_launch(void* const* d_in, const int* in_sizes, int n_in,
                              void* d_out, int out_size, void* d_ws, size_t ws_size,
                              hipStream_t stream) {
    const float* logit = (const float*)d_in[0];
    float* out = (float*)d_out;
    unsigned int* packed = (unsigned int*)d_ws;  // 8 MB

    k1_entropy_argmax<<<HW / 1024, 256, 0, stream>>>(logit, packed);
    k23_box_score<<<256, NT, 0, stream>>>(packed, out, out + HW, out + 2 * HW);
}